// Round 8
// baseline (197.323 us; speedup 1.0000x reference)
//
#include <hip/hip_runtime.h>
#include <hip/hip_bf16.h>

#define DEG        16
#define IN_FEATS   256
#define NUM_HEADS  4
#define OUT_FEATS  64
#define HF         256
#define NEG_SLOPE  0.2f

#define CPITCH 264     // 256 + 8 (epilogue store-transpose pitch)

typedef __attribute__((ext_vector_type(8))) short  short8;
typedef __attribute__((ext_vector_type(4))) float  floatx4;
typedef unsigned short ushortT;

__device__ __forceinline__ unsigned short f2bf(float f) {
    union { float f; unsigned u; } v; v.f = f;
    unsigned r = v.u + 0x7fffu + ((v.u >> 16) & 1u);   // round-to-nearest-even
    return (unsigned short)(r >> 16);
}
// bf16 unpack: guaranteed 1 VALU each (shift / and)
__device__ __forceinline__ float bf_lo(unsigned u) {
    union { unsigned x; float f; } v; v.x = u << 16; return v.f;
}
__device__ __forceinline__ float bf_hi(unsigned u) {
    union { unsigned x; float f; } v; v.x = u & 0xffff0000u; return v.f;
}
// packed fp32x2 -> bf16x2 (manual RTNE pack; verified absmax since round 2)
__device__ __forceinline__ unsigned cvt2(float lo, float hi) {
    return (unsigned)f2bf(lo) | ((unsigned)f2bf(hi) << 16);
}

// ---------------------------------------------------------------------------
// Kernel 0: Wt[n][k] = bf16(W[k][n])  (256x256, tiny)
// ---------------------------------------------------------------------------
__global__ __launch_bounds__(256) void conv_wt(
    const float* __restrict__ W, ushortT* __restrict__ Wt)
{
    int n = blockIdx.x;
    int k = threadIdx.x;
    Wt[n * 256 + k] = f2bf(W[k * 256 + n]);
}

// ---------------------------------------------------------------------------
// Kernel 1: h = feat @ W via MFMA bf16 (BYTE-IDENTICAL to verified version).
// ---------------------------------------------------------------------------
__global__ __launch_bounds__(256, 3) void gat_gemm_fused(
    const float* __restrict__ feat,           // fp32 [M,256]
    const ushortT* __restrict__ Bt,           // Wt bf16 [n=256][k=256]
    const float* __restrict__ attn_l,         // [256]
    const float* __restrict__ attn_r,         // [256]
    ushortT* __restrict__ Hb,                 // h bf16 [M,256]
    float* __restrict__ arow,                 // [M,4]
    float* __restrict__ acol,                 // [M,4]
    int M)
{
    // As: 64 rows x 32 chunks x 16B = 32 KB (XOR-swizzled). Cs overlays.
    __shared__ __align__(16) ushortT SMEM[64 * CPITCH];
    ushortT* As = SMEM;
    ushortT* Cs = SMEM;

    const int tid  = threadIdx.x;
    const int wave = tid >> 6;       // == head
    const int lane = tid & 63;
    const int l15  = lane & 15;
    const int quad = lane >> 4;
    const int rowBase = blockIdx.x * 64;

    // ---- Prefetch B for ks=0 (independent of LDS staging).
    short8 bbuf[2][4];
    #pragma unroll
    for (int ni = 0; ni < 4; ++ni)
        bbuf[0][ni] = *(const short8*)&Bt[(wave * 64 + ni * 16 + l15) * 256 + quad * 8];

    // ---- Stage A: 64 rows x 256 cols fp32 -> bf16 swizzled LDS.
    #pragma unroll
    for (int pass = 0; pass < 2; ++pass) {
        float4 v[8];
        #pragma unroll
        for (int i = 0; i < 8; ++i) {
            int id  = pass * 2048 + i * 256 + tid;   // flat float4 index
            int row = id >> 6;                        // 64 float4 per row
            int c4  = id & 63;
            int gr  = rowBase + row; if (gr > M - 1) gr = M - 1;
            v[i] = *(const float4*)&feat[(size_t)gr * 256 + c4 * 4];
        }
        #pragma unroll
        for (int i = 0; i < 8; ++i) {
            int id   = pass * 2048 + i * 256 + tid;
            int row  = id >> 6;
            int c4   = id & 63;
            int cg   = c4 >> 1;                       // 16B chunk col (0..31)
            int half = c4 & 1;
            uint2 w = make_uint2(cvt2(v[i].x, v[i].y), cvt2(v[i].z, v[i].w));
            *(uint2*)&As[row * 256 + ((cg ^ (row & 7)) << 3) + half * 4] = w;
        }
    }

    __syncthreads();

    floatx4 acc[4][4] = {};

    #pragma unroll
    for (int ks = 0; ks < 8; ++ks) {
        if (ks < 7) {
            #pragma unroll
            for (int ni = 0; ni < 4; ++ni)
                bbuf[(ks + 1) & 1][ni] = *(const short8*)
                    &Bt[(wave * 64 + ni * 16 + l15) * 256 + (ks + 1) * 32 + quad * 8];
        }
        short8 af[4];
        #pragma unroll
        for (int mi = 0; mi < 4; ++mi) {
            int row = mi * 16 + l15;
            int q   = ks * 4 + quad;
            int cst = q ^ (row & 7);
            af[mi] = *(const short8*)&As[row * 256 + cst * 8];
        }
        #pragma unroll
        for (int mi = 0; mi < 4; ++mi)
            #pragma unroll
            for (int ni = 0; ni < 4; ++ni)
                acc[mi][ni] = __builtin_amdgcn_mfma_f32_16x16x32_bf16(
                    af[mi], bbuf[ks & 1][ni], acc[mi][ni], 0, 0, 0);
    }

    // ---- Epilogue A: attention scores (wave == head).
    float al[4], ar[4];
    #pragma unroll
    for (int ni = 0; ni < 4; ++ni) {
        al[ni] = attn_l[wave * 64 + ni * 16 + l15];
        ar[ni] = attn_r[wave * 64 + ni * 16 + l15];
    }
    #pragma unroll
    for (int mi = 0; mi < 4; ++mi) {
        #pragma unroll
        for (int reg = 0; reg < 4; ++reg) {
            float pl = 0.f, pr = 0.f;
            #pragma unroll
            for (int ni = 0; ni < 4; ++ni) {
                pl = fmaf(acc[mi][ni][reg], al[ni], pl);
                pr = fmaf(acc[mi][ni][reg], ar[ni], pr);
            }
            #pragma unroll
            for (int off = 8; off >= 1; off >>= 1) {
                pl += __shfl_xor(pl, off, 64);   // stays within 16-lane quad
                pr += __shfl_xor(pr, off, 64);
            }
            if (l15 == 0) {
                int gr = rowBase + mi * 16 + quad * 4 + reg;
                if (gr < M) {
                    arow[gr * NUM_HEADS + wave] = pl;
                    acol[gr * NUM_HEADS + wave] = pr;
                }
            }
        }
    }

    __syncthreads();   // all As reads complete before Cs overlay

    // ---- Epilogue B: h -> bf16, coalesced row-major store via LDS transpose.
    #pragma unroll
    for (int mi = 0; mi < 4; ++mi)
        #pragma unroll
        for (int ni = 0; ni < 4; ++ni)
            #pragma unroll
            for (int reg = 0; reg < 4; ++reg)
                Cs[(mi * 16 + quad * 4 + reg) * CPITCH + wave * 64 + ni * 16 + l15] =
                    f2bf(acc[mi][ni][reg]);
    __syncthreads();

    #pragma unroll
    for (int i = 0; i < 8; ++i) {
        int f  = tid + 256 * i;
        int r  = f >> 5;
        int c8 = (f & 31) << 3;
        int gr = rowBase + r;
        if (gr < M) {
            uint4 v = *(const uint4*)&Cs[r * CPITCH + c8];
            *(uint4*)&Hb[(size_t)gr * HF + c8] = v;
        }
    }
}

// ---------------------------------------------------------------------------
// Kernel 2 (v9s): TWO NODES PER WAVE, 16 GATHERS IN FLIGHT — WINDOWED.
// Identical math to round-7-verified v9; takes an [n0,n1) node window so the
// launcher can split the aggregate into 3 sequential dispatches of ~21 us.
// DIAGNOSTIC PURPOSE: top-5 rocprof rows only ever show the slowest kernel;
// at 63 us the aggregate masked gat_gemm_fused entirely.  With 21-us parts,
// gemm surfaces in top-5 iff it exceeds ~21 us -> next round gets counters
// for the unaccounted ~128 us non-aggregate budget.
// ---------------------------------------------------------------------------
__global__ __launch_bounds__(256) void gat_aggregate9(
    const ushortT* __restrict__ Hb,          // bf16 [N,256]
    const float* __restrict__ arow,          // [N,4]
    const float* __restrict__ acol,          // [N,4]
    const int* __restrict__ col_ind,         // [N*16]
    float* __restrict__ out,                 // [N,256] fp32
    int n0, int n1)                           // node window [n0, n1)
{
    const int tid  = threadIdx.x;
    const int wave = tid >> 6;
    const int lane = tid & 63;
    const int gw   = blockIdx.x * 4 + wave;   // wave id within this window

    int nA = n0 + gw * 2;
    if (nA >= n1) return;
    int nB = nA + 1;
    const bool hasB = (nB < n1);
    if (!hasB) nB = nA;                       // safe duplicate, store guarded

    const int j16  = lane & 15;
    const int hd16 = lane >> 4;

    // ---- Softmax for both nodes (lane = head*16 + edge, verified layout).
    int srcA = col_ind[nA * DEG + j16];
    int srcB = col_ind[nB * DEG + j16];
    float eA = arow[nA * NUM_HEADS + hd16] + acol[srcA * NUM_HEADS + hd16];
    float eB = arow[nB * NUM_HEADS + hd16] + acol[srcB * NUM_HEADS + hd16];
    eA = (eA > 0.f) ? eA : NEG_SLOPE * eA;
    eB = (eB > 0.f) ? eB : NEG_SLOPE * eB;

    float mA = eA, mB = eB;
    #pragma unroll
    for (int off = 8; off >= 1; off >>= 1) {
        mA = fmaxf(mA, __shfl_xor(mA, off, 16));
        mB = fmaxf(mB, __shfl_xor(mB, off, 16));
    }
    float exA = __expf(eA - mA), exB = __expf(eB - mB);
    float sA = exA, sB = exB;
    #pragma unroll
    for (int off = 8; off >= 1; off >>= 1) {
        sA += __shfl_xor(sA, off, 16);
        sB += __shfl_xor(sB, off, 16);
    }
    float alA = exA / sA;                    // alpha[head=hd16][edge=j16]
    float alB = exB / sB;

    // ---- Aggregation: dual-edge layout per node (verified v4 mapping).
    const int l32     = lane & 31;
    const int half    = lane >> 5;
    const int headSel = (l32 >> 3) << 4;

    int   sjA[8], sjB[8];
    float avA[8], avB[8];
    #pragma unroll
    for (int j = 0; j < 8; ++j) {
        int ep = (j << 1) + half;                     // edge 0..15
        sjA[j] = __shfl(srcA, ep, 64);
        avA[j] = __shfl(alA, headSel + ep, 64);
        sjB[j] = __shfl(srcB, ep, 64);
        avB[j] = __shfl(alB, headSel + ep, 64);
    }

    // 16 loads issued back-to-back: 16 outstanding misses per wave.
    uint4 vA[8], vB[8];
    #pragma unroll
    for (int j = 0; j < 8; ++j)
        vA[j] = *(const uint4*)&Hb[(size_t)sjA[j] * HF + l32 * 8];
    #pragma unroll
    for (int j = 0; j < 8; ++j)
        vB[j] = *(const uint4*)&Hb[(size_t)sjB[j] * HF + l32 * 8];

    __builtin_amdgcn_sched_barrier(0);   // loads may not sink below

    float accA[8] = {}, accB[8] = {};
    #pragma unroll
    for (int j = 0; j < 8; ++j) {
        accA[0] = fmaf(avA[j], bf_lo(vA[j].x), accA[0]);
        accA[1] = fmaf(avA[j], bf_hi(vA[j].x), accA[1]);
        accA[2] = fmaf(avA[j], bf_lo(vA[j].y), accA[2]);
        accA[3] = fmaf(avA[j], bf_hi(vA[j].y), accA[3]);
        accA[4] = fmaf(avA[j], bf_lo(vA[j].z), accA[4]);
        accA[5] = fmaf(avA[j], bf_hi(vA[j].z), accA[5]);
        accA[6] = fmaf(avA[j], bf_lo(vA[j].w), accA[6]);
        accA[7] = fmaf(avA[j], bf_hi(vA[j].w), accA[7]);
    }
    #pragma unroll
    for (int j = 0; j < 8; ++j) {
        accB[0] = fmaf(avB[j], bf_lo(vB[j].x), accB[0]);
        accB[1] = fmaf(avB[j], bf_hi(vB[j].x), accB[1]);
        accB[2] = fmaf(avB[j], bf_lo(vB[j].y), accB[2]);
        accB[3] = fmaf(avB[j], bf_hi(vB[j].y), accB[3]);
        accB[4] = fmaf(avB[j], bf_lo(vB[j].z), accB[4]);
        accB[5] = fmaf(avB[j], bf_hi(vB[j].z), accB[5]);
        accB[6] = fmaf(avB[j], bf_lo(vB[j].w), accB[6]);
        accB[7] = fmaf(avB[j], bf_hi(vB[j].w), accB[7]);
    }

    #pragma unroll
    for (int i = 0; i < 8; ++i) {
        accA[i] += __shfl_xor(accA[i], 32, 64);
        accB[i] += __shfl_xor(accB[i], 32, 64);
    }

    float4 oA, oB;
    if (half == 0) {
        oA = make_float4(accA[0], accA[1], accA[2], accA[3]);
        oB = make_float4(accB[0], accB[1], accB[2], accB[3]);
    } else {
        oA = make_float4(accA[4], accA[5], accA[6], accA[7]);
        oB = make_float4(accB[4], accB[5], accB[6], accB[7]);
    }
    *(float4*)&out[(size_t)nA * HF + l32 * 8 + half * 4] = oA;
    if (hasB)
        *(float4*)&out[(size_t)nB * HF + l32 * 8 + half * 4] = oB;
}

// ---------------------------------------------------------------------------
extern "C" void kernel_launch(void* const* d_in, const int* in_sizes, int n_in,
                              void* d_out, int out_size, void* d_ws, size_t ws_size,
                              hipStream_t stream) {
    // Inputs: row_ptr, col_ind, col_ptr, row_ind, feat, W, attn_l, attn_r
    const int*   col_ind = (const int*)  d_in[1];
    const float* feat    = (const float*)d_in[4];
    const float* W       = (const float*)d_in[5];
    const float* attn_l  = (const float*)d_in[6];
    const float* attn_r  = (const float*)d_in[7];
    float* out = (float*)d_out;

    const int N = in_sizes[0] - 1;   // 50000

    // ws: Hb bf16 [N*256] | arow f32 [N*4] | acol f32 [N*4] | Wt bf16 [64K]
    ushortT* Hb   = (ushortT*)d_ws;
    float*   arow = (float*)(Hb + (size_t)N * HF);
    float*   acol = arow + (size_t)N * NUM_HEADS;
    ushortT* Wt   = (ushortT*)(acol + (size_t)N * NUM_HEADS);

    conv_wt<<<256, 256, 0, stream>>>(W, Wt);

    dim3 ggrid((N + 63) / 64);
    gat_gemm_fused<<<ggrid, 256, 0, stream>>>(feat, Wt, attn_l, attn_r,
                                              Hb, arow, acol, N);

    // Aggregate split into 3 sequential windows (~N/3 nodes each, even
    // sizes) purely so each dispatch is ~21 us -> rocprof top-5 threshold
    // drops and gat_gemm_fused becomes visible if it exceeds ~21 us.
    int c = ((N + 2) / 3) & ~1;              // even chunk (16666 for N=50000)
    int starts[3] = { 0, c, 2 * c };
    for (int p = 0; p < 3; ++p) {
        int s = starts[p];
        int e = (p == 2) ? N : starts[p] + c;
        if (s >= e) continue;
        int nb = (e - s + 7) / 8;            // 2 nodes/wave, 8 nodes/block
        gat_aggregate9<<<nb, 256, 0, stream>>>(Hb, arow, acol, col_ind,
                                               out, s, e);
    }
}

// Round 9
// 195.578 us; speedup vs baseline: 1.0089x; 1.0089x over previous
//
#include <hip/hip_runtime.h>
#include <hip/hip_bf16.h>

#define DEG        16
#define IN_FEATS   256
#define NUM_HEADS  4
#define OUT_FEATS  64
#define HF         256
#define NEG_SLOPE  0.2f

#define CPITCH 264     // 256 + 8 (epilogue store-transpose pitch)

typedef __attribute__((ext_vector_type(8))) short  short8;
typedef __attribute__((ext_vector_type(4))) float  floatx4;
typedef unsigned short ushortT;

__device__ __forceinline__ unsigned short f2bf(float f) {
    union { float f; unsigned u; } v; v.f = f;
    unsigned r = v.u + 0x7fffu + ((v.u >> 16) & 1u);   // round-to-nearest-even
    return (unsigned short)(r >> 16);
}
// bf16 unpack: guaranteed 1 VALU each (shift / and)
__device__ __forceinline__ float bf_lo(unsigned u) {
    union { unsigned x; float f; } v; v.x = u << 16; return v.f;
}
__device__ __forceinline__ float bf_hi(unsigned u) {
    union { unsigned x; float f; } v; v.x = u & 0xffff0000u; return v.f;
}
// packed fp32x2 -> bf16x2 (manual RTNE pack; verified absmax since round 2)
__device__ __forceinline__ unsigned cvt2(float lo, float hi) {
    return (unsigned)f2bf(lo) | ((unsigned)f2bf(hi) << 16);
}

// ---------------------------------------------------------------------------
// Kernel 0: Wt[n][k] = bf16(W[k][n])  (256x256, tiny)
// ---------------------------------------------------------------------------
__global__ __launch_bounds__(256) void conv_wt(
    const float* __restrict__ W, ushortT* __restrict__ Wt)
{
    int n = blockIdx.x;
    int k = threadIdx.x;
    Wt[n * 256 + k] = f2bf(W[k * 256 + n]);
}

// ---------------------------------------------------------------------------
// Kernel 1 (v2): 32-ROW TILES FOR 2x GRID PARALLELISM.
// Round-8 diagnosis: 64-row version ran 42 us (3x its ~13 us roofline) at
// 20% occupancy, 5% MfmaUtil — latency-bound, only 782 blocks (~1.6
// resident/CU) with a long serial chain per block.  v2: 32-row tile ->
// 1563 blocks, LDS 16.9 KB (8 blocks/CU), staging is ONE 8-deep load
// batch (was 2 serial passes), per-block work halves.  No launch_bounds
// min-wave clause (v7 spill lesson).  Math identical per row; B path,
// swizzle, epilogues unchanged except mi ranges.
// ---------------------------------------------------------------------------
__global__ __launch_bounds__(256) void gat_gemm_fused(
    const float* __restrict__ feat,           // fp32 [M,256]
    const ushortT* __restrict__ Bt,           // Wt bf16 [n=256][k=256]
    const float* __restrict__ attn_l,         // [256]
    const float* __restrict__ attn_r,         // [256]
    ushortT* __restrict__ Hb,                 // h bf16 [M,256]
    float* __restrict__ arow,                 // [M,4]
    float* __restrict__ acol,                 // [M,4]
    int M)
{
    // As: 32 rows x 32 chunks x 16B = 16 KB (XOR-swizzled). Cs overlays.
    __shared__ __align__(16) ushortT SMEM[32 * CPITCH];
    ushortT* As = SMEM;
    ushortT* Cs = SMEM;

    const int tid  = threadIdx.x;
    const int wave = tid >> 6;       // == head
    const int lane = tid & 63;
    const int l15  = lane & 15;
    const int quad = lane >> 4;
    const int rowBase = blockIdx.x * 32;

    // ---- Prefetch B for ks=0 (independent of LDS staging).
    short8 bbuf[2][4];
    #pragma unroll
    for (int ni = 0; ni < 4; ++ni)
        bbuf[0][ni] = *(const short8*)&Bt[(wave * 64 + ni * 16 + l15) * 256 + quad * 8];

    // ---- Stage A: 32 rows x 256 cols fp32 -> bf16 swizzled LDS.
    // 2048 float4s total; ONE batch of 8 per thread (all in flight).
    // Layout: 16B chunk cg of row r stored at chunk (cg ^ (r&7))  [verified].
    {
        float4 v[8];
        #pragma unroll
        for (int i = 0; i < 8; ++i) {
            int id  = i * 256 + tid;                  // flat float4 index
            int row = id >> 6;                        // 64 float4 per row
            int c4  = id & 63;
            int gr  = rowBase + row; if (gr > M - 1) gr = M - 1;
            v[i] = *(const float4*)&feat[(size_t)gr * 256 + c4 * 4];
        }
        #pragma unroll
        for (int i = 0; i < 8; ++i) {
            int id   = i * 256 + tid;
            int row  = id >> 6;
            int c4   = id & 63;
            int cg   = c4 >> 1;                       // 16B chunk col (0..31)
            int half = c4 & 1;
            uint2 w = make_uint2(cvt2(v[i].x, v[i].y), cvt2(v[i].z, v[i].w));
            *(uint2*)&As[row * 256 + ((cg ^ (row & 7)) << 3) + half * 4] = w;
        }
    }

    __syncthreads();

    floatx4 acc[2][4] = {};

    #pragma unroll
    for (int ks = 0; ks < 8; ++ks) {
        if (ks < 7) {
            #pragma unroll
            for (int ni = 0; ni < 4; ++ni)
                bbuf[(ks + 1) & 1][ni] = *(const short8*)
                    &Bt[(wave * 64 + ni * 16 + l15) * 256 + (ks + 1) * 32 + quad * 8];
        }
        short8 af[2];
        #pragma unroll
        for (int mi = 0; mi < 2; ++mi) {
            int row = mi * 16 + l15;
            int q   = ks * 4 + quad;
            int cst = q ^ (row & 7);
            af[mi] = *(const short8*)&As[row * 256 + cst * 8];
        }
        #pragma unroll
        for (int mi = 0; mi < 2; ++mi)
            #pragma unroll
            for (int ni = 0; ni < 4; ++ni)
                acc[mi][ni] = __builtin_amdgcn_mfma_f32_16x16x32_bf16(
                    af[mi], bbuf[ks & 1][ni], acc[mi][ni], 0, 0, 0);
    }

    // ---- Epilogue A: attention scores (wave == head).
    float al[4], ar[4];
    #pragma unroll
    for (int ni = 0; ni < 4; ++ni) {
        al[ni] = attn_l[wave * 64 + ni * 16 + l15];
        ar[ni] = attn_r[wave * 64 + ni * 16 + l15];
    }
    #pragma unroll
    for (int mi = 0; mi < 2; ++mi) {
        #pragma unroll
        for (int reg = 0; reg < 4; ++reg) {
            float pl = 0.f, pr = 0.f;
            #pragma unroll
            for (int ni = 0; ni < 4; ++ni) {
                pl = fmaf(acc[mi][ni][reg], al[ni], pl);
                pr = fmaf(acc[mi][ni][reg], ar[ni], pr);
            }
            #pragma unroll
            for (int off = 8; off >= 1; off >>= 1) {
                pl += __shfl_xor(pl, off, 64);   // stays within 16-lane quad
                pr += __shfl_xor(pr, off, 64);
            }
            if (l15 == 0) {
                int gr = rowBase + mi * 16 + quad * 4 + reg;
                if (gr < M) {
                    arow[gr * NUM_HEADS + wave] = pl;
                    acol[gr * NUM_HEADS + wave] = pr;
                }
            }
        }
    }

    __syncthreads();   // all As reads complete before Cs overlay

    // ---- Epilogue B: h -> bf16, coalesced row-major store via LDS transpose.
    #pragma unroll
    for (int mi = 0; mi < 2; ++mi)
        #pragma unroll
        for (int ni = 0; ni < 4; ++ni)
            #pragma unroll
            for (int reg = 0; reg < 4; ++reg)
                Cs[(mi * 16 + quad * 4 + reg) * CPITCH + wave * 64 + ni * 16 + l15] =
                    f2bf(acc[mi][ni][reg]);
    __syncthreads();

    #pragma unroll
    for (int i = 0; i < 4; ++i) {
        int f  = tid + 256 * i;
        int r  = f >> 5;                     // 0..31
        int c8 = (f & 31) << 3;
        int gr = rowBase + r;
        if (gr < M) {
            uint4 v = *(const uint4*)&Cs[r * CPITCH + c8];
            *(uint4*)&Hb[(size_t)gr * HF + c8] = v;
        }
    }
}

// ---------------------------------------------------------------------------
// Kernel 2 (v9, round-7 verified): TWO NODES PER WAVE, 16 GATHERS IN FLIGHT.
// Single dispatch again (the round-8 3-way split was diagnostic-only and
// cost ~7 us in launch overhead).  63 us = memory-system plateau for this
// random-gather pattern (invariant across churn/batch/persistent variants).
// ---------------------------------------------------------------------------
__global__ __launch_bounds__(256) void gat_aggregate9(
    const ushortT* __restrict__ Hb,          // bf16 [N,256]
    const float* __restrict__ arow,          // [N,4]
    const float* __restrict__ acol,          // [N,4]
    const int* __restrict__ col_ind,         // [N*16]
    float* __restrict__ out,                 // [N,256] fp32
    int N)
{
    const int tid  = threadIdx.x;
    const int wave = tid >> 6;
    const int lane = tid & 63;
    const int gw   = blockIdx.x * 4 + wave;   // global wave id

    int nA = gw * 2;
    if (nA >= N) return;
    int nB = nA + 1;
    const bool hasB = (nB < N);
    if (!hasB) nB = nA;                       // safe duplicate, store guarded

    const int j16  = lane & 15;
    const int hd16 = lane >> 4;

    // ---- Softmax for both nodes (lane = head*16 + edge, verified layout).
    int srcA = col_ind[nA * DEG + j16];
    int srcB = col_ind[nB * DEG + j16];
    float eA = arow[nA * NUM_HEADS + hd16] + acol[srcA * NUM_HEADS + hd16];
    float eB = arow[nB * NUM_HEADS + hd16] + acol[srcB * NUM_HEADS + hd16];
    eA = (eA > 0.f) ? eA : NEG_SLOPE * eA;
    eB = (eB > 0.f) ? eB : NEG_SLOPE * eB;

    float mA = eA, mB = eB;
    #pragma unroll
    for (int off = 8; off >= 1; off >>= 1) {
        mA = fmaxf(mA, __shfl_xor(mA, off, 16));
        mB = fmaxf(mB, __shfl_xor(mB, off, 16));
    }
    float exA = __expf(eA - mA), exB = __expf(eB - mB);
    float sA = exA, sB = exB;
    #pragma unroll
    for (int off = 8; off >= 1; off >>= 1) {
        sA += __shfl_xor(sA, off, 16);
        sB += __shfl_xor(sB, off, 16);
    }
    float alA = exA / sA;                    // alpha[head=hd16][edge=j16]
    float alB = exB / sB;

    // ---- Aggregation: dual-edge layout per node (verified v4 mapping).
    const int l32     = lane & 31;
    const int half    = lane >> 5;
    const int headSel = (l32 >> 3) << 4;

    int   sjA[8], sjB[8];
    float avA[8], avB[8];
    #pragma unroll
    for (int j = 0; j < 8; ++j) {
        int ep = (j << 1) + half;                     // edge 0..15
        sjA[j] = __shfl(srcA, ep, 64);
        avA[j] = __shfl(alA, headSel + ep, 64);
        sjB[j] = __shfl(srcB, ep, 64);
        avB[j] = __shfl(alB, headSel + ep, 64);
    }

    // 16 loads issued back-to-back: 16 outstanding misses per wave.
    uint4 vA[8], vB[8];
    #pragma unroll
    for (int j = 0; j < 8; ++j)
        vA[j] = *(const uint4*)&Hb[(size_t)sjA[j] * HF + l32 * 8];
    #pragma unroll
    for (int j = 0; j < 8; ++j)
        vB[j] = *(const uint4*)&Hb[(size_t)sjB[j] * HF + l32 * 8];

    __builtin_amdgcn_sched_barrier(0);   // loads may not sink below

    float accA[8] = {}, accB[8] = {};
    #pragma unroll
    for (int j = 0; j < 8; ++j) {
        accA[0] = fmaf(avA[j], bf_lo(vA[j].x), accA[0]);
        accA[1] = fmaf(avA[j], bf_hi(vA[j].x), accA[1]);
        accA[2] = fmaf(avA[j], bf_lo(vA[j].y), accA[2]);
        accA[3] = fmaf(avA[j], bf_hi(vA[j].y), accA[3]);
        accA[4] = fmaf(avA[j], bf_lo(vA[j].z), accA[4]);
        accA[5] = fmaf(avA[j], bf_hi(vA[j].z), accA[5]);
        accA[6] = fmaf(avA[j], bf_lo(vA[j].w), accA[6]);
        accA[7] = fmaf(avA[j], bf_hi(vA[j].w), accA[7]);
    }
    #pragma unroll
    for (int j = 0; j < 8; ++j) {
        accB[0] = fmaf(avB[j], bf_lo(vB[j].x), accB[0]);
        accB[1] = fmaf(avB[j], bf_hi(vB[j].x), accB[1]);
        accB[2] = fmaf(avB[j], bf_lo(vB[j].y), accB[2]);
        accB[3] = fmaf(avB[j], bf_hi(vB[j].y), accB[3]);
        accB[4] = fmaf(avB[j], bf_lo(vB[j].z), accB[4]);
        accB[5] = fmaf(avB[j], bf_hi(vB[j].z), accB[5]);
        accB[6] = fmaf(avB[j], bf_lo(vB[j].w), accB[6]);
        accB[7] = fmaf(avB[j], bf_hi(vB[j].w), accB[7]);
    }

    #pragma unroll
    for (int i = 0; i < 8; ++i) {
        accA[i] += __shfl_xor(accA[i], 32, 64);
        accB[i] += __shfl_xor(accB[i], 32, 64);
    }

    float4 oA, oB;
    if (half == 0) {
        oA = make_float4(accA[0], accA[1], accA[2], accA[3]);
        oB = make_float4(accB[0], accB[1], accB[2], accB[3]);
    } else {
        oA = make_float4(accA[4], accA[5], accA[6], accA[7]);
        oB = make_float4(accB[4], accB[5], accB[6], accB[7]);
    }
    *(float4*)&out[(size_t)nA * HF + l32 * 8 + half * 4] = oA;
    if (hasB)
        *(float4*)&out[(size_t)nB * HF + l32 * 8 + half * 4] = oB;
}

// ---------------------------------------------------------------------------
extern "C" void kernel_launch(void* const* d_in, const int* in_sizes, int n_in,
                              void* d_out, int out_size, void* d_ws, size_t ws_size,
                              hipStream_t stream) {
    // Inputs: row_ptr, col_ind, col_ptr, row_ind, feat, W, attn_l, attn_r
    const int*   col_ind = (const int*)  d_in[1];
    const float* feat    = (const float*)d_in[4];
    const float* W       = (const float*)d_in[5];
    const float* attn_l  = (const float*)d_in[6];
    const float* attn_r  = (const float*)d_in[7];
    float* out = (float*)d_out;

    const int N = in_sizes[0] - 1;   // 50000

    // ws: Hb bf16 [N*256] | arow f32 [N*4] | acol f32 [N*4] | Wt bf16 [64K]
    ushortT* Hb   = (ushortT*)d_ws;
    float*   arow = (float*)(Hb + (size_t)N * HF);
    float*   acol = arow + (size_t)N * NUM_HEADS;
    ushortT* Wt   = (ushortT*)(acol + (size_t)N * NUM_HEADS);

    conv_wt<<<256, 256, 0, stream>>>(W, Wt);

    dim3 ggrid((N + 31) / 32);               // 32-row tiles
    gat_gemm_fused<<<ggrid, 256, 0, stream>>>(feat, Wt, attn_l, attn_r,
                                              Hb, arow, acol, N);

    // 2 nodes per wave, 8 nodes per block (round-7 verified single dispatch).
    gat_aggregate9<<<(N + 7) / 8, 256, 0, stream>>>(Hb, arow, acol, col_ind, out, N);
}